// Round 1
// baseline (407.259 us; speedup 1.0000x reference)
//
#include <hip/hip_runtime.h>
#include <hip/hip_bf16.h>

// ---------- types ----------
typedef __attribute__((ext_vector_type(4))) float  f32x4;
typedef __attribute__((ext_vector_type(8))) __bf16 bf16x8;
typedef __attribute__((ext_vector_type(8))) short  short8;

#define BM 128
#define BN 128
#define BK 32

__device__ inline unsigned short f2bf(float f) {
    union { float f; unsigned u; } v; v.f = f;
    unsigned r = v.u + 0x7fffu + ((v.u >> 16) & 1u);   // RNE
    return (unsigned short)(r >> 16);
}

// ---------- kernel 1: dequant weight codes -> bf16 [N][K] ----------
__global__ void dequant_w(const int* __restrict__ wq, const float* __restrict__ absmax,
                          const float* __restrict__ code, short* __restrict__ wout) {
    __shared__ float cs[256];
    cs[threadIdx.x] = code[threadIdx.x];
    __syncthreads();
    size_t idx = ((size_t)blockIdx.x * blockDim.x + threadIdx.x) * 8;
    float am = absmax[idx >> 12];                      // BLOCKSIZE = 4096
    int4 q0 = *(const int4*)(wq + idx);
    int4 q1 = *(const int4*)(wq + idx + 4);
    short8 r;
    r[0] = (short)f2bf(cs[q0.x] * am);
    r[1] = (short)f2bf(cs[q0.y] * am);
    r[2] = (short)f2bf(cs[q0.z] * am);
    r[3] = (short)f2bf(cs[q0.w] * am);
    r[4] = (short)f2bf(cs[q1.x] * am);
    r[5] = (short)f2bf(cs[q1.y] * am);
    r[6] = (short)f2bf(cs[q1.z] * am);
    r[7] = (short)f2bf(cs[q1.w] * am);
    *(short8*)(wout + idx) = r;
}

// ---------- kernel 2: x fp32 -> bf16 [M][K] ----------
__global__ void cvt_x(const float* __restrict__ xin, short* __restrict__ xout) {
    size_t idx = ((size_t)blockIdx.x * blockDim.x + threadIdx.x) * 8;
    float4 a = *(const float4*)(xin + idx);
    float4 b = *(const float4*)(xin + idx + 4);
    short8 r;
    r[0] = (short)f2bf(a.x); r[1] = (short)f2bf(a.y);
    r[2] = (short)f2bf(a.z); r[3] = (short)f2bf(a.w);
    r[4] = (short)f2bf(b.x); r[5] = (short)f2bf(b.y);
    r[6] = (short)f2bf(b.z); r[7] = (short)f2bf(b.w);
    *(short8*)(xout + idx) = r;
}

// ---------- kernel 3: bf16 NT GEMM, C = A[M,K] * B[N,K]^T + bias, fp32 out ----------
__global__ __launch_bounds__(256) void gemm_bf16(
    const short* __restrict__ A,   // [M][K] bf16 bits
    const short* __restrict__ Bm,  // [N][K] bf16 bits
    const float* __restrict__ bias,
    float* __restrict__ C, int M, int N, int K) {

    __shared__ short lsA[BM * BK];   // 8 KB
    __shared__ short lsB[BN * BK];   // 8 KB

    const int tid  = threadIdx.x;
    const int w    = tid >> 6;
    const int lane = tid & 63;
    const int wr   = w >> 1;         // wave row 0..1 (64-row half)
    const int wc   = w & 1;          // wave col 0..1 (64-col half)
    const int bRow = blockIdx.y * BM;
    const int bCol = blockIdx.x * BN;

    f32x4 acc[4][4] = {};

    const int lr = lane & 15;            // fragment row/col within 16
    const int kk = (lane >> 4) * 8;      // fragment k offset

    // staging: wave w owns 1KB chunks {2w, 2w+1} of each 8KB tile
    const int c0   = w * 2;
    const int srow = lane >> 2;          // 0..15 within chunk
    const int skc  = (lane & 3) * 8;     // k element offset

    for (int k0 = 0; k0 < K; k0 += BK) {
        #pragma unroll
        for (int i = 0; i < 2; ++i) {
            int c = c0 + i;
            const short* ga = A  + (size_t)(bRow + 16 * c + srow) * K + k0 + skc;
            const short* gb = Bm + (size_t)(bCol + 16 * c + srow) * K + k0 + skc;
            __builtin_amdgcn_global_load_lds(
                (const __attribute__((address_space(1))) short*)ga,
                (__attribute__((address_space(3))) short*)&lsA[c * 512], 16, 0, 0);
            __builtin_amdgcn_global_load_lds(
                (const __attribute__((address_space(1))) short*)gb,
                (__attribute__((address_space(3))) short*)&lsB[c * 512], 16, 0, 0);
        }
        __syncthreads();

        bf16x8 af[4], bfr[4];
        #pragma unroll
        for (int m = 0; m < 4; ++m)
            af[m] = *(const bf16x8*)&lsA[(wr * 64 + m * 16 + lr) * BK + kk];
        #pragma unroll
        for (int n = 0; n < 4; ++n)
            bfr[n] = *(const bf16x8*)&lsB[(wc * 64 + n * 16 + lr) * BK + kk];

        #pragma unroll
        for (int m = 0; m < 4; ++m)
            #pragma unroll
            for (int n = 0; n < 4; ++n)
                acc[m][n] = __builtin_amdgcn_mfma_f32_16x16x32_bf16(af[m], bfr[n], acc[m][n], 0, 0, 0);
        __syncthreads();
    }

    // epilogue: C/D layout col = lane&15, row = (lane>>4)*4 + reg
    float bv[4];
    #pragma unroll
    for (int n = 0; n < 4; ++n) bv[n] = bias[bCol + wc * 64 + n * 16 + lr];

    #pragma unroll
    for (int m = 0; m < 4; ++m) {
        int row0 = bRow + wr * 64 + m * 16 + (lane >> 4) * 4;
        #pragma unroll
        for (int n = 0; n < 4; ++n) {
            int col = bCol + wc * 64 + n * 16 + lr;
            f32x4 v = acc[m][n];
            #pragma unroll
            for (int j = 0; j < 4; ++j)
                C[(size_t)(row0 + j) * N + col] = v[j] + bv[n];
        }
    }
}

extern "C" void kernel_launch(void* const* d_in, const int* in_sizes, int n_in,
                              void* d_out, int out_size, void* d_ws, size_t ws_size,
                              hipStream_t stream) {
    const float* x      = (const float*)d_in[0];
    const int*   wq     = (const int*)  d_in[1];
    const float* absmax = (const float*)d_in[2];
    const float* code   = (const float*)d_in[3];
    const float* bias   = (const float*)d_in[4];
    float* out = (float*)d_out;

    const int K = 4096, N = 4096;
    const int M = in_sizes[0] / K;            // 8192

    short* wbf = (short*)d_ws;                // [N][K] bf16: 32 MiB
    short* xbf = wbf + (size_t)N * K;         // [M][K] bf16: 64 MiB

    dequant_w<<<(size_t)N * K / 8 / 256, 256, 0, stream>>>(wq, absmax, code, wbf);
    cvt_x    <<<(size_t)M * K / 8 / 256, 256, 0, stream>>>(x, xbf);

    dim3 grid(N / BN, M / BM);
    gemm_bf16<<<grid, 256, 0, stream>>>(xbf, wbf, bias, out, M, N, K);
}

// Round 2
// 297.709 us; speedup vs baseline: 1.3680x; 1.3680x over previous
//
#include <hip/hip_runtime.h>
#include <hip/hip_bf16.h>

typedef __attribute__((ext_vector_type(4))) float  f32x4;
typedef __attribute__((ext_vector_type(8))) __bf16 bf16x8;
typedef __attribute__((ext_vector_type(8))) short  short8;

#define KDIM 4096
#define NDIM 4096
#define BK   64
#define NT   (KDIM / BK)     // 64 K-tiles

__device__ inline unsigned short f2bf(float f) {
    union { float f; unsigned u; } v; v.f = f;
    unsigned r = v.u + 0x7fffu + ((v.u >> 16) & 1u);   // RNE
    return (unsigned short)(r >> 16);
}

// ---------- kernel 1: dequant weight codes -> bf16 [N][K] ----------
__global__ void dequant_w(const int* __restrict__ wq, const float* __restrict__ absmax,
                          const float* __restrict__ code, short* __restrict__ wout) {
    __shared__ float cs[256];
    cs[threadIdx.x] = code[threadIdx.x];
    __syncthreads();
    size_t idx = ((size_t)blockIdx.x * blockDim.x + threadIdx.x) * 8;
    float am = absmax[idx >> 12];                      // BLOCKSIZE = 4096
    int4 q0 = *(const int4*)(wq + idx);
    int4 q1 = *(const int4*)(wq + idx + 4);
    short8 r;
    r[0] = (short)f2bf(cs[q0.x] * am);
    r[1] = (short)f2bf(cs[q0.y] * am);
    r[2] = (short)f2bf(cs[q0.z] * am);
    r[3] = (short)f2bf(cs[q0.w] * am);
    r[4] = (short)f2bf(cs[q1.x] * am);
    r[5] = (short)f2bf(cs[q1.y] * am);
    r[6] = (short)f2bf(cs[q1.z] * am);
    r[7] = (short)f2bf(cs[q1.w] * am);
    *(short8*)(wout + idx) = r;
}

// ---------- kernel 2: x fp32 -> bf16 [M][K] ----------
__global__ void cvt_x(const float* __restrict__ xin, short* __restrict__ xout) {
    size_t idx = ((size_t)blockIdx.x * blockDim.x + threadIdx.x) * 8;
    float4 a = *(const float4*)(xin + idx);
    float4 b = *(const float4*)(xin + idx + 4);
    short8 r;
    r[0] = (short)f2bf(a.x); r[1] = (short)f2bf(a.y);
    r[2] = (short)f2bf(a.z); r[3] = (short)f2bf(a.w);
    r[4] = (short)f2bf(b.x); r[5] = (short)f2bf(b.y);
    r[6] = (short)f2bf(b.z); r[7] = (short)f2bf(b.w);
    *(short8*)(xout + idx) = r;
}

// ---------- kernel 3: 256x256 8-phase bf16 NT GEMM (m201 template) ----------
// C = A[M,K] * B[N,K]^T + bias.  8 waves; per phase all waves compute one
// 128x128 C-quadrant over K=64 (16 MFMA/wave).  LDS: 2 buf x (A[256][64] +
// B[256][64]) bf16 = 128 KiB, st_16x32 swizzle (byte ^= ((byte>>9)&1)<<5)
// applied via pre-swizzled global source (linear global_load_lds dest) and
// swizzled ds_read addresses.  vmcnt(6) only at phases 4/8.
__global__ __launch_bounds__(512, 2) void gemm256(
    const short* __restrict__ A, const short* __restrict__ Bm,
    const float* __restrict__ bias, float* __restrict__ C, int M) {

    __shared__ __attribute__((aligned(128))) char lds[131072];

    const int tid  = threadIdx.x;
    const int wid  = tid >> 6;
    const int lane = tid & 63;
    const int wr   = wid >> 2;        // 0..1 : 64-row piece within quadrant
    const int wc   = wid & 3;         // 0..3 : 32-col piece within quadrant
    const int lr   = lane & 15;
    const int kl   = (lane >> 4) * 8; // k element offset of fragment

    // XCD-aware chunked swizzle (512 wg, %8==0 -> simple form is bijective)
    const int nwg  = gridDim.x;
    const int cpx  = nwg >> 3;
    const int swzb = (blockIdx.x & 7) * cpx + (blockIdx.x >> 3);
    const int bx   = swzb & 15;              // NDIM/256 = 16 tiles, fastest
    const int by   = swzb >> 4;
    const int tileM = by * 256, tileN = bx * 256;

    // ---- read-side constants (swizzle bit = ((row>>2)&1)<<5 = per-lane const)
    const int swb = ((lr >> 2) & 1) << 5;
    const int kb0 = (kl * 2) ^ swb;
    const int kb1 = ((kl + 32) * 2) ^ swb;
    const int arow = (wr * 64 + lr) * 128;   // region-relative byte row base
    const int brow = (wc * 32 + lr) * 128;

    // ---- staging constants: linear LDS dest (t*16), pre-swizzled global src
    const int u0 = (tid * 16) ^ (((tid >> 5) & 1) << 5);
    const int u1 = (8192 + tid * 16) ^ (((tid >> 5) & 1) << 5);
    const int srow0 = u0 >> 7, scol0 = (u0 & 127) >> 1;   // rows 0..63
    const int srow1 = u1 >> 7, scol1 = (u1 & 127) >> 1;   // rows 64..127

    const short* pA0 = A  + (size_t)(tileM + srow0) * KDIM + scol0;
    const short* pA1 = A  + (size_t)(tileM + srow1) * KDIM + scol1;
    const short* pB0 = Bm + (size_t)(tileN + srow0) * KDIM + scol0;
    const short* pB1 = Bm + (size_t)(tileN + srow1) * KDIM + scol1;

#define LDSA(b) (lds + (b) * 65536)
#define LDSB(b) (lds + (b) * 65536 + 32768)

#define STAGE(PM0, PM1, REG, H, KS) do {                                       \
    char* _l = (REG) + (H) * 16384 + wid * 1024;                               \
    __builtin_amdgcn_global_load_lds(                                          \
        (const __attribute__((address_space(1))) void*)((PM0) + (size_t)(H) * 128 * KDIM + (KS)), \
        (__attribute__((address_space(3))) void*)(_l), 16, 0, 0);              \
    __builtin_amdgcn_global_load_lds(                                          \
        (const __attribute__((address_space(1))) void*)((PM1) + (size_t)(H) * 128 * KDIM + (KS)), \
        (__attribute__((address_space(3))) void*)(_l + 8192), 16, 0, 0);       \
} while (0)

    f32x4  acc[2][2][4][2] = {};   // [qr][qc][mi][ni]
    bf16x8 aF[4][2], bF[2][2];     // [mi][ks], [ni][ks]

#define RDA(b, QR) do {                                                        \
    _Pragma("unroll") for (int mi = 0; mi < 4; ++mi) {                         \
        const char* _p = LDSA(b) + (QR) * 16384 + mi * 2048 + arow;            \
        aF[mi][0] = *(const bf16x8*)(_p + kb0);                                \
        aF[mi][1] = *(const bf16x8*)(_p + kb1);                                \
    } } while (0)

#define RDB(b, QC) do {                                                        \
    _Pragma("unroll") for (int ni = 0; ni < 2; ++ni) {                         \
        const char* _p = LDSB(b) + (QC) * 16384 + ni * 2048 + brow;            \
        bF[ni][0] = *(const bf16x8*)(_p + kb0);                                \
        bF[ni][1] = *(const bf16x8*)(_p + kb1);                                \
    } } while (0)

#define MFMA16(QR, QC) do {                                                    \
    __builtin_amdgcn_s_setprio(1);                                             \
    _Pragma("unroll") for (int ks = 0; ks < 2; ++ks)                           \
    _Pragma("unroll") for (int mi = 0; mi < 4; ++mi)                           \
    _Pragma("unroll") for (int ni = 0; ni < 2; ++ni)                           \
        acc[QR][QC][mi][ni] = __builtin_amdgcn_mfma_f32_16x16x32_bf16(         \
            aF[mi][ks], bF[ni][ks], acc[QR][QC][mi][ni], 0, 0, 0);             \
    __builtin_amdgcn_s_setprio(0);                                             \
} while (0)

#define BAR()       __builtin_amdgcn_s_barrier()
#define WAIT_LGKM() do { asm volatile("s_waitcnt lgkmcnt(0)" ::: "memory");    \
                         __builtin_amdgcn_sched_barrier(0); } while (0)
#define WAIT_VM6()  asm volatile("s_waitcnt vmcnt(6)" ::: "memory")

    // ---- prologue: tile0 (all 4 halves) + tile1 (A-lo, B-hi, A-hi; B-lo in-loop)
    STAGE(pA0, pA1, LDSA(0), 0, 0);
    STAGE(pA0, pA1, LDSA(0), 1, 0);
    STAGE(pB0, pB1, LDSB(0), 0, 0);
    STAGE(pB0, pB1, LDSB(0), 1, 0);
    STAGE(pA0, pA1, LDSA(1), 0, BK);
    STAGE(pB0, pB1, LDSB(1), 1, BK);
    STAGE(pA0, pA1, LDSA(1), 1, BK);
    WAIT_VM6();
    BAR();

    // ---- main loop: 2 K-tiles (8 phases) per iteration
    for (int it = 0; it < NT / 2; ++it) {
        const int k1 = ((2 * it + 1) * BK) & (KDIM - 1);
        const int k2 = ((2 * it + 2) * BK) & (KDIM - 1);
        const int k3 = ((2 * it + 3) * BK) & (KDIM - 1);

        // ---- tile 2it (buf0) ----
        RDA(0, 0); RDB(0, 0);                  // Ph1: quad(0,0)
        STAGE(pB0, pB1, LDSB(1), 0, k1);       //   B-lo(t+1) -> buf1
        BAR(); WAIT_LGKM(); MFMA16(0, 0); BAR();

        RDB(0, 1);                             // Ph2: quad(0,1), reuse aF
        STAGE(pA0, pA1, LDSA(0), 0, k2);       //   A-lo(t+2) -> buf0
        BAR(); WAIT_LGKM(); MFMA16(0, 1); BAR();

        RDA(0, 1);                             // Ph3: quad(1,1), reuse bF
        STAGE(pB0, pB1, LDSB(0), 1, k2);       //   B-hi(t+2) -> buf0
        BAR(); WAIT_LGKM(); MFMA16(1, 1); BAR();

        RDB(0, 0);                             // Ph4: quad(1,0), reuse aF
        STAGE(pA0, pA1, LDSA(0), 1, k2);       //   A-hi(t+2) -> buf0
        BAR(); WAIT_LGKM(); MFMA16(1, 0);
        WAIT_VM6(); BAR();

        // ---- tile 2it+1 (buf1) ----
        RDA(1, 0); RDB(1, 0);                  // Ph5: quad(0,0)
        STAGE(pB0, pB1, LDSB(0), 0, k2);       //   B-lo(t+2) -> buf0
        BAR(); WAIT_LGKM(); MFMA16(0, 0); BAR();

        RDB(1, 1);                             // Ph6: quad(0,1)
        STAGE(pA0, pA1, LDSA(1), 0, k3);       //   A-lo(t+3) -> buf1
        BAR(); WAIT_LGKM(); MFMA16(0, 1); BAR();

        RDA(1, 1);                             // Ph7: quad(1,1)
        STAGE(pB0, pB1, LDSB(1), 1, k3);       //   B-hi(t+3) -> buf1
        BAR(); WAIT_LGKM(); MFMA16(1, 1); BAR();

        RDB(1, 0);                             // Ph8: quad(1,0)
        STAGE(pA0, pA1, LDSA(1), 1, k3);       //   A-hi(t+3) -> buf1
        BAR(); WAIT_LGKM(); MFMA16(1, 0);
        WAIT_VM6(); BAR();
    }

    // ---- epilogue: C = acc + bias
    const int r4 = (lane >> 4) * 4;
    float bv[2][2];
    #pragma unroll
    for (int qc = 0; qc < 2; ++qc)
        #pragma unroll
        for (int ni = 0; ni < 2; ++ni)
            bv[qc][ni] = bias[tileN + qc * 128 + wc * 32 + ni * 16 + lr];

    #pragma unroll
    for (int qr = 0; qr < 2; ++qr)
    #pragma unroll
    for (int qc = 0; qc < 2; ++qc)
    #pragma unroll
    for (int mi = 0; mi < 4; ++mi)
    #pragma unroll
    for (int ni = 0; ni < 2; ++ni) {
        const int row0 = tileM + qr * 128 + wr * 64 + mi * 16 + r4;
        const int col  = tileN + qc * 128 + wc * 32 + ni * 16 + lr;
        f32x4 v = acc[qr][qc][mi][ni];
        #pragma unroll
        for (int j = 0; j < 4; ++j)
            C[(size_t)(row0 + j) * NDIM + col] = v[j] + bv[qc][ni];
    }
}

extern "C" void kernel_launch(void* const* d_in, const int* in_sizes, int n_in,
                              void* d_out, int out_size, void* d_ws, size_t ws_size,
                              hipStream_t stream) {
    const float* x      = (const float*)d_in[0];
    const int*   wq     = (const int*)  d_in[1];
    const float* absmax = (const float*)d_in[2];
    const float* code   = (const float*)d_in[3];
    const float* bias   = (const float*)d_in[4];
    float* out = (float*)d_out;

    const int K = KDIM, N = NDIM;
    const int M = in_sizes[0] / K;            // 8192

    short* wbf = (short*)d_ws;                // [N][K] bf16: 32 MiB
    short* xbf = wbf + (size_t)N * K;         // [M][K] bf16: 64 MiB

    dequant_w<<<(size_t)N * K / 8 / 256, 256, 0, stream>>>(wq, absmax, code, wbf);
    cvt_x    <<<(size_t)M * K / 8 / 256, 256, 0, stream>>>(x, xbf);

    const int nwg = (M / 256) * (N / 256);    // 512, %8 == 0
    gemm256<<<nwg, 512, 0, stream>>>(xbf, wbf, bias, out, M);
}

// Round 3
// 275.394 us; speedup vs baseline: 1.4788x; 1.0810x over previous
//
#include <hip/hip_runtime.h>
#include <hip/hip_bf16.h>

typedef __attribute__((ext_vector_type(4))) float  f32x4;
typedef __attribute__((ext_vector_type(8))) __bf16 bf16x8;
typedef __attribute__((ext_vector_type(8))) short  short8;

#define KDIM 4096
#define NDIM 4096
#define BK   64
#define NT   (KDIM / BK)     // 64 K-tiles

__device__ inline unsigned short f2bf(float f) {
    union { float f; unsigned u; } v; v.f = f;
    unsigned r = v.u + 0x7fffu + ((v.u >> 16) & 1u);   // RNE
    return (unsigned short)(r >> 16);
}

// ---------- kernel 1: dequant weight codes -> bf16 [N][K] ----------
__global__ void dequant_w(const int* __restrict__ wq, const float* __restrict__ absmax,
                          const float* __restrict__ code, short* __restrict__ wout) {
    __shared__ float cs[256];
    cs[threadIdx.x] = code[threadIdx.x];
    __syncthreads();
    size_t idx = ((size_t)blockIdx.x * blockDim.x + threadIdx.x) * 8;
    float am = absmax[idx >> 12];                      // BLOCKSIZE = 4096
    int4 q0 = *(const int4*)(wq + idx);
    int4 q1 = *(const int4*)(wq + idx + 4);
    short8 r;
    r[0] = (short)f2bf(cs[q0.x] * am);
    r[1] = (short)f2bf(cs[q0.y] * am);
    r[2] = (short)f2bf(cs[q0.z] * am);
    r[3] = (short)f2bf(cs[q0.w] * am);
    r[4] = (short)f2bf(cs[q1.x] * am);
    r[5] = (short)f2bf(cs[q1.y] * am);
    r[6] = (short)f2bf(cs[q1.z] * am);
    r[7] = (short)f2bf(cs[q1.w] * am);
    *(short8*)(wout + idx) = r;
}

// ---------- kernel 2: x fp32 -> bf16 [M][K] ----------
__global__ void cvt_x(const float* __restrict__ xin, short* __restrict__ xout) {
    size_t idx = ((size_t)blockIdx.x * blockDim.x + threadIdx.x) * 8;
    float4 a = *(const float4*)(xin + idx);
    float4 b = *(const float4*)(xin + idx + 4);
    short8 r;
    r[0] = (short)f2bf(a.x); r[1] = (short)f2bf(a.y);
    r[2] = (short)f2bf(a.z); r[3] = (short)f2bf(a.w);
    r[4] = (short)f2bf(b.x); r[5] = (short)f2bf(b.y);
    r[6] = (short)f2bf(b.z); r[7] = (short)f2bf(b.w);
    *(short8*)(xout + idx) = r;
}

// ---------- kernel 3: 256x256 8-phase bf16 NT GEMM ----------
// C = A[M,K] * B[N,K]^T + bias.  8 waves; per phase all waves compute one
// 128x128 C-quadrant over K=64 (16 MFMA/wave).  LDS: 2 buf x (A[256][64] +
// B[256][64]) bf16 = 128 KiB.
// Swizzle (3-bit, conflict-free): logical byte a within a 16KB half-region,
// S(a) = ((a>>7)&7)<<4  (XOR row bits 0-2 into colbyte bits 4-6).
// Applied as: linear global_load_lds dest + source address pre-XORed with S,
// and ds_read at a^S(a).  Involution: S only reads bits 7-9, XOR hits 4-6.
__global__ __launch_bounds__(512, 2) void gemm256(
    const short* __restrict__ A, const short* __restrict__ Bm,
    const float* __restrict__ bias, float* __restrict__ C, int M) {

    __shared__ __attribute__((aligned(128))) char lds[131072];

    const int tid  = threadIdx.x;
    const int wid  = tid >> 6;
    const int lane = tid & 63;
    const int wr   = wid >> 2;        // 0..1 : 64-row piece within quadrant
    const int wc   = wid & 3;         // 0..3 : 32-col piece within quadrant
    const int lr   = lane & 15;
    const int kl   = (lane >> 4) * 8; // k element offset of fragment

    // XCD-aware chunked swizzle (512 wg, %8==0 -> simple form is bijective)
    const int nwg  = gridDim.x;
    const int cpx  = nwg >> 3;
    const int swzb = (blockIdx.x & 7) * cpx + (blockIdx.x >> 3);
    const int bx   = swzb & 15;              // NDIM/256 = 16 tiles, fastest
    const int by   = swzb >> 4;
    const int tileM = by * 256, tileN = bx * 256;

    // ---- read-side swizzle: row&7 == lr&7 for both A and B fragments
    const int swb = (lr & 7) << 4;
    const int kb0 = (kl * 2) ^ swb;
    const int kb1 = (kl * 2 + 64) ^ swb;
    const int arow = (wr * 64 + lr) * 128;   // region-relative byte row base
    const int brow = (wc * 32 + lr) * 128;

    // ---- staging: linear LDS dest (t*16), source pre-XORed with S
    const int u0 = (tid * 16) ^ (((tid >> 3) & 7) << 4);
    const int u1 = (8192 + tid * 16) ^ (((tid >> 3) & 7) << 4);
    const int srow0 = u0 >> 7, scol0 = (u0 & 127) >> 1;   // rows 0..63
    const int srow1 = u1 >> 7, scol1 = (u1 & 127) >> 1;   // rows 64..127

    const short* pA0 = A  + (size_t)(tileM + srow0) * KDIM + scol0;
    const short* pA1 = A  + (size_t)(tileM + srow1) * KDIM + scol1;
    const short* pB0 = Bm + (size_t)(tileN + srow0) * KDIM + scol0;
    const short* pB1 = Bm + (size_t)(tileN + srow1) * KDIM + scol1;

#define LDSA(b) (lds + (b) * 65536)
#define LDSB(b) (lds + (b) * 65536 + 32768)

#define STAGE(PM0, PM1, REG, H, KS) do {                                       \
    char* _l = (REG) + (H) * 16384 + wid * 1024;                               \
    __builtin_amdgcn_global_load_lds(                                          \
        (const __attribute__((address_space(1))) void*)((PM0) + (size_t)(H) * 128 * KDIM + (KS)), \
        (__attribute__((address_space(3))) void*)(_l), 16, 0, 0);              \
    __builtin_amdgcn_global_load_lds(                                          \
        (const __attribute__((address_space(1))) void*)((PM1) + (size_t)(H) * 128 * KDIM + (KS)), \
        (__attribute__((address_space(3))) void*)(_l + 8192), 16, 0, 0);       \
} while (0)

    f32x4  acc[2][2][4][2] = {};   // [qr][qc][mi][ni]
    bf16x8 aF[4][2], bF[2][2];     // [mi][ks], [ni][ks]

#define RDA(b, QR) do {                                                        \
    _Pragma("unroll") for (int mi = 0; mi < 4; ++mi) {                         \
        const char* _p = LDSA(b) + (QR) * 16384 + mi * 2048 + arow;            \
        aF[mi][0] = *(const bf16x8*)(_p + kb0);                                \
        aF[mi][1] = *(const bf16x8*)(_p + kb1);                                \
    } } while (0)

#define RDB(b, QC) do {                                                        \
    _Pragma("unroll") for (int ni = 0; ni < 2; ++ni) {                         \
        const char* _p = LDSB(b) + (QC) * 16384 + ni * 2048 + brow;            \
        bF[ni][0] = *(const bf16x8*)(_p + kb0);                                \
        bF[ni][1] = *(const bf16x8*)(_p + kb1);                                \
    } } while (0)

#define MFMA16(QR, QC) do {                                                    \
    __builtin_amdgcn_s_setprio(1);                                             \
    _Pragma("unroll") for (int ks = 0; ks < 2; ++ks)                           \
    _Pragma("unroll") for (int mi = 0; mi < 4; ++mi)                           \
    _Pragma("unroll") for (int ni = 0; ni < 2; ++ni)                           \
        acc[QR][QC][mi][ni] = __builtin_amdgcn_mfma_f32_16x16x32_bf16(         \
            aF[mi][ks], bF[ni][ks], acc[QR][QC][mi][ni], 0, 0, 0);             \
    __builtin_amdgcn_s_setprio(0);                                             \
} while (0)

#define BAR()       __builtin_amdgcn_s_barrier()
#define WAIT_LGKM() do { asm volatile("s_waitcnt lgkmcnt(0)" ::: "memory");    \
                         __builtin_amdgcn_sched_barrier(0); } while (0)
#define WAIT_VM6()  asm volatile("s_waitcnt vmcnt(6)" ::: "memory")

    // ---- prologue: tile0 (all 4 halves) + tile1 (A-lo, B-hi, A-hi; B-lo in-loop)
    STAGE(pA0, pA1, LDSA(0), 0, 0);
    STAGE(pA0, pA1, LDSA(0), 1, 0);
    STAGE(pB0, pB1, LDSB(0), 0, 0);
    STAGE(pB0, pB1, LDSB(0), 1, 0);
    STAGE(pA0, pA1, LDSA(1), 0, BK);
    STAGE(pB0, pB1, LDSB(1), 1, BK);
    STAGE(pA0, pA1, LDSA(1), 1, BK);
    WAIT_VM6();
    BAR();

    // ---- main loop: 2 K-tiles (8 phases) per iteration
    for (int it = 0; it < NT / 2; ++it) {
        const int k1 = ((2 * it + 1) * BK) & (KDIM - 1);
        const int k2 = ((2 * it + 2) * BK) & (KDIM - 1);
        const int k3 = ((2 * it + 3) * BK) & (KDIM - 1);

        // ---- tile 2it (buf0) ----
        RDA(0, 0); RDB(0, 0);                  // Ph1: quad(0,0)
        STAGE(pB0, pB1, LDSB(1), 0, k1);       //   B-lo(t+1) -> buf1
        BAR(); WAIT_LGKM(); MFMA16(0, 0); BAR();

        RDB(0, 1);                             // Ph2: quad(0,1), reuse aF
        STAGE(pA0, pA1, LDSA(0), 0, k2);       //   A-lo(t+2) -> buf0
        BAR(); WAIT_LGKM(); MFMA16(0, 1); BAR();

        RDA(0, 1);                             // Ph3: quad(1,1), reuse bF
        STAGE(pB0, pB1, LDSB(0), 1, k2);       //   B-hi(t+2) -> buf0
        BAR(); WAIT_LGKM(); MFMA16(1, 1); BAR();

        RDB(0, 0);                             // Ph4: quad(1,0), reuse aF
        STAGE(pA0, pA1, LDSA(0), 1, k2);       //   A-hi(t+2) -> buf0
        BAR(); WAIT_LGKM(); MFMA16(1, 0);
        WAIT_VM6(); BAR();

        // ---- tile 2it+1 (buf1) ----
        RDA(1, 0); RDB(1, 0);                  // Ph5: quad(0,0)
        STAGE(pB0, pB1, LDSB(0), 0, k2);       //   B-lo(t+2) -> buf0
        BAR(); WAIT_LGKM(); MFMA16(0, 0); BAR();

        RDB(1, 1);                             // Ph6: quad(0,1)
        STAGE(pA0, pA1, LDSA(1), 0, k3);       //   A-lo(t+3) -> buf1
        BAR(); WAIT_LGKM(); MFMA16(0, 1); BAR();

        RDA(1, 1);                             // Ph7: quad(1,1)
        STAGE(pB0, pB1, LDSB(1), 1, k3);       //   B-hi(t+3) -> buf1
        BAR(); WAIT_LGKM(); MFMA16(1, 1); BAR();

        RDB(1, 0);                             // Ph8: quad(1,0)
        STAGE(pA0, pA1, LDSA(1), 1, k3);       //   A-hi(t+3) -> buf1
        BAR(); WAIT_LGKM(); MFMA16(1, 0);
        WAIT_VM6(); BAR();
    }

    // ---- epilogue: C = acc + bias
    const int r4 = (lane >> 4) * 4;
    float bv[2][2];
    #pragma unroll
    for (int qc = 0; qc < 2; ++qc)
        #pragma unroll
        for (int ni = 0; ni < 2; ++ni)
            bv[qc][ni] = bias[tileN + qc * 128 + wc * 32 + ni * 16 + lr];

    #pragma unroll
    for (int qr = 0; qr < 2; ++qr)
    #pragma unroll
    for (int qc = 0; qc < 2; ++qc)
    #pragma unroll
    for (int mi = 0; mi < 4; ++mi)
    #pragma unroll
    for (int ni = 0; ni < 2; ++ni) {
        const int row0 = tileM + qr * 128 + wr * 64 + mi * 16 + r4;
        const int col  = tileN + qc * 128 + wc * 32 + ni * 16 + lr;
        f32x4 v = acc[qr][qc][mi][ni];
        #pragma unroll
        for (int j = 0; j < 4; ++j)
            C[(size_t)(row0 + j) * NDIM + col] = v[j] + bv[qc][ni];
    }
}

extern "C" void kernel_launch(void* const* d_in, const int* in_sizes, int n_in,
                              void* d_out, int out_size, void* d_ws, size_t ws_size,
                              hipStream_t stream) {
    const float* x      = (const float*)d_in[0];
    const int*   wq     = (const int*)  d_in[1];
    const float* absmax = (const float*)d_in[2];
    const float* code   = (const float*)d_in[3];
    const float* bias   = (const float*)d_in[4];
    float* out = (float*)d_out;

    const int K = KDIM, N = NDIM;
    const int M = in_sizes[0] / K;            // 8192

    short* wbf = (short*)d_ws;                // [N][K] bf16: 32 MiB
    short* xbf = wbf + (size_t)N * K;         // [M][K] bf16: 64 MiB

    dequant_w<<<(size_t)N * K / 8 / 256, 256, 0, stream>>>(wq, absmax, code, wbf);
    cvt_x    <<<(size_t)M * K / 8 / 256, 256, 0, stream>>>(x, xbf);

    const int nwg = (M / 256) * (N / 256);    // 512, %8 == 0
    gemm256<<<nwg, 512, 0, stream>>>(xbf, wbf, bias, out, M);
}